// Round 4
// baseline (110.387 us; speedup 1.0000x reference)
//
#include <hip/hip_runtime.h>
#include <hip/hip_bf16.h>

// GraphSAGE 2-layer forward, fp32.
// B=512, S0=25, S1=10, IN_DIM=256, HID=128 (concat->256), N_CLASSES=7.

constexpr int IN    = 256;
constexpr int HIDC  = 128;        // per-branch hidden
constexpr int BM    = 16;         // rows per block in k_gemm
constexpr int ROWS1 = 512 * 25;   // 12800

// ---------------- Kernel A: m2[r] = mean10(f2 rows) -------------------------
// One wave per row: 64 lanes x float4 = 1KB row. 10 independent gathers/wave.
__global__ __launch_bounds__(512) void k_mean(
    const int* __restrict__ ids2, const float* __restrict__ feats,
    float* __restrict__ m2)
{
    const int wave = threadIdx.x >> 6;
    const int lane = threadIdx.x & 63;
    const int r    = blockIdx.x * 8 + wave;
    const int base = r * 10;
    float4 acc = make_float4(0.f, 0.f, 0.f, 0.f);
    #pragma unroll
    for (int kk = 0; kk < 10; ++kk) {
        const float4* p = (const float4*)(feats + (size_t)ids2[base + kk] * IN);
        const float4 v = p[lane];
        acc.x += v.x; acc.y += v.y; acc.z += v.z; acc.w += v.w;
    }
    acc.x *= 0.1f; acc.y *= 0.1f; acc.z *= 0.1f; acc.w *= 0.1f;
    ((float4*)(m2 + (size_t)r * IN))[lane] = acc;
}

// ---------------- Kernel B: h1 = relu([f1@Wx1+b, m2@Wn1+b]) -----------------
// One block = 16 rows x ONE branch (128 cols). NB = blockIdx.x & 1.
// 16 KB LDS -> 10 blocks/CU cap; grid 1600 -> ~25 waves/CU.
// Per thread: 4 rows x 2 cols (8:1 FMA:load).
__global__ __launch_bounds__(256) void k_gemm(
    const int* __restrict__ ids1, const float* __restrict__ feats,
    const float* __restrict__ m2,
    const float* __restrict__ Wx, const float* __restrict__ bx,
    const float* __restrict__ Wn, const float* __restrict__ bn,
    float* __restrict__ h1)
{
    __shared__ float A[BM][IN];
    const int tid = threadIdx.x;
    const int NB  = blockIdx.x & 1;          // 0 = self branch, 1 = neighbor branch
    const int r0  = (blockIdx.x >> 1) * BM;

    // staging: 4 rows in parallel, 64 threads/row, float4 (1KB/row coalesced)
    const int sub = tid & 63;
    const int rg  = tid >> 6;
    #pragma unroll
    for (int i = 0; i < BM; i += 4) {
        const int rr = rg + i;
        const int r  = r0 + rr;
        const float* src = NB ? (m2 + (size_t)r * IN)
                              : (feats + (size_t)ids1[r] * IN);
        ((float4*)A[rr])[sub] = ((const float4*)src)[sub];
    }
    __syncthreads();

    // compute: thread -> colpair j (cols 2j,2j+1 of this branch's 128),
    //          row group g (rows g*4 .. g*4+3)
    const int j  = tid & 63;
    const int g  = tid >> 6;
    const int cc = 2 * j;
    const float* __restrict__ bias = NB ? bn : bx;
    const float  b0 = bias[cc];
    const float  b1 = bias[cc + 1];
    const float2* __restrict__ W2 = (const float2*)(NB ? Wn : Wx); // [256][64] pairs

    float acc0[4] = {0.f, 0.f, 0.f, 0.f};
    float acc1[4] = {0.f, 0.f, 0.f, 0.f};

    for (int k = 0; k < IN; k += 4) {
        float4 av[4];
        #pragma unroll
        for (int rr = 0; rr < 4; ++rr)
            av[rr] = *(const float4*)&A[g * 4 + rr][k];   // wave-uniform broadcast
        #pragma unroll
        for (int kk = 0; kk < 4; ++kk) {
            const float2 w = W2[(size_t)(k + kk) * 64 + j];
            #pragma unroll
            for (int rr = 0; rr < 4; ++rr) {
                const float a = (&av[rr].x)[kk];
                acc0[rr] = fmaf(a, w.x, acc0[rr]);
                acc1[rr] = fmaf(a, w.y, acc1[rr]);
            }
        }
    }
    #pragma unroll
    for (int rr = 0; rr < 4; ++rr) {
        const int r = r0 + g * 4 + rr;
        float2 v;
        v.x = fmaxf(acc0[rr] + b0, 0.f);
        v.y = fmaxf(acc1[rr] + b1, 0.f);
        *(float2*)&h1[(size_t)r * IN + NB * HIDC + cc] = v;
    }
}

// ---------------- Kernel C: per output row, 512 threads ---------------------
__global__ __launch_bounds__(512) void k_out(
    const int* __restrict__ ids, const int* __restrict__ ids1,
    const float* __restrict__ feats, const float* __restrict__ h1,
    const float* __restrict__ Wx1, const float* __restrict__ bx1,
    const float* __restrict__ Wn1, const float* __restrict__ bn1,
    const float* __restrict__ Wx2, const float* __restrict__ bx2,
    const float* __restrict__ Wn2, const float* __restrict__ bn2,
    const float* __restrict__ Wfc, const float* __restrict__ bfc,
    float* __restrict__ out)
{
    __shared__ float x0[IN];
    __shared__ float m1[IN];
    __shared__ float mh[IN];
    __shared__ float h0[IN];
    __shared__ float g0[IN];
    __shared__ float partA[2][IN];
    __shared__ float partB[2][IN];
    __shared__ float red[8];
    __shared__ float fcred[7][4];
    const int i   = blockIdx.x;
    const int tid = threadIdx.x;
    const int c   = tid & 255;
    const int h   = tid >> 8;

    float s = 0.f, sh = 0.f;
    for (int kk = h; kk < 25; kk += 2) {
        const int r = i * 25 + kk;
        s  += feats[(size_t)ids1[r] * IN + c];
        sh += h1[(size_t)r * IN + c];
    }
    if (h == 0) x0[c] = feats[(size_t)ids[i] * IN + c];
    partA[h][c] = s;
    partB[h][c] = sh;
    __syncthreads();
    if (h == 0) m1[c] = (partA[0][c] + partA[1][c]) * 0.04f;
    else        mh[c] = (partB[0][c] + partB[1][c]) * 0.04f;
    __syncthreads();

    const int  jj = c & 127;
    const bool nb = (c >= 128);
    {
        const float* __restrict__ W = nb ? Wn1 : Wx1;
        const float* __restrict__ X = nb ? m1 : x0;
        float acc = 0.f;
        #pragma unroll 4
        for (int k = h * 128; k < h * 128 + 128; ++k)
            acc = fmaf(X[k], W[(size_t)k * HIDC + jj], acc);
        partA[h][c] = acc;
    }
    __syncthreads();
    if (h == 0)
        h0[c] = fmaxf(partA[0][c] + partA[1][c] + (nb ? bn1 : bx1)[jj], 0.f);
    __syncthreads();
    {
        const float* __restrict__ W = nb ? Wn2 : Wx2;
        const float* __restrict__ X = nb ? mh : h0;
        float acc = 0.f;
        #pragma unroll 4
        for (int k = h * 128; k < h * 128 + 128; ++k)
            acc = fmaf(X[k], W[(size_t)k * HIDC + jj], acc);
        partB[h][c] = acc;
    }
    __syncthreads();
    if (h == 0)
        g0[c] = partB[0][c] + partB[1][c] + (nb ? bn2 : bx2)[jj];
    __syncthreads();

    {
        const float gv = g0[c];
        float sq = gv * gv;
        #pragma unroll
        for (int off = 32; off > 0; off >>= 1) sq += __shfl_down(sq, off);
        if ((tid & 63) == 0) red[tid >> 6] = sq;
    }
    __syncthreads();
    const float total = (red[0] + red[1] + red[2] + red[3] +
                         red[4] + red[5] + red[6] + red[7]) * 0.5f;
    const float inv = 1.f / fmaxf(sqrtf(total), 1e-12f);
    const float p = g0[c] * inv;

    const int qbase = h * 4;
    const int qn    = h ? 3 : 4;
    for (int q = qbase; q < qbase + qn; ++q) {
        float t = p * Wfc[(size_t)c * 7 + q];
        #pragma unroll
        for (int off = 32; off > 0; off >>= 1) t += __shfl_down(t, off);
        if ((tid & 63) == 0) fcred[q][(tid >> 6) & 3] = t;
    }
    __syncthreads();
    if (tid < 7) {
        out[(size_t)i * 7 + tid] =
            fcred[tid][0] + fcred[tid][1] + fcred[tid][2] + fcred[tid][3] + bfc[tid];
    }
}

extern "C" void kernel_launch(void* const* d_in, const int* in_sizes, int n_in,
                              void* d_out, int out_size, void* d_ws, size_t ws_size,
                              hipStream_t stream) {
    const int*   ids   = (const int*)d_in[0];
    const int*   ids1  = (const int*)d_in[1];
    const int*   ids2  = (const int*)d_in[2];
    const float* feats = (const float*)d_in[3];
    const float* Wx1   = (const float*)d_in[4];
    const float* bx1   = (const float*)d_in[5];
    const float* Wn1   = (const float*)d_in[6];
    const float* bn1   = (const float*)d_in[7];
    const float* Wx2   = (const float*)d_in[8];
    const float* bx2   = (const float*)d_in[9];
    const float* Wn2   = (const float*)d_in[10];
    const float* bn2   = (const float*)d_in[11];
    const float* Wfc   = (const float*)d_in[12];
    const float* bfc   = (const float*)d_in[13];
    float* out = (float*)d_out;
    float* m2  = (float*)d_ws;                        // [12800][256] = 13.1 MB
    float* h1  = (float*)d_ws + (size_t)ROWS1 * IN;   // [12800][256] = 13.1 MB

    k_mean<<<ROWS1 / 8, 512, 0, stream>>>(ids2, feats, m2);
    k_gemm<<<(ROWS1 / BM) * 2, 256, 0, stream>>>(ids1, feats, m2,
                                                 Wx1, bx1, Wn1, bn1, h1);
    k_out<<<512, 512, 0, stream>>>(ids, ids1, feats, h1,
                                   Wx1, bx1, Wn1, bn1,
                                   Wx2, bx2, Wn2, bn2,
                                   Wfc, bfc, out);
}

// Round 5
// 95.939 us; speedup vs baseline: 1.1506x; 1.1506x over previous
//
#include <hip/hip_runtime.h>
#include <hip/hip_bf16.h>

// GraphSAGE 2-layer forward. fp32 everywhere except layer-1 GEMM, which uses
// bf16 hi/lo split MFMA (3 passes: Ah*Wh + Ah*Wl + Al*Wh ~ fp32 precision).

typedef __bf16 bf16x8 __attribute__((ext_vector_type(8)));
typedef __bf16 bf16x4 __attribute__((ext_vector_type(4)));
typedef float  f32x4  __attribute__((ext_vector_type(4)));

constexpr int IN    = 256;
constexpr int HIDC  = 128;
constexpr int ROWS1 = 512 * 25;   // 12800
constexpr int BRM   = 32;         // rows per k_gemm block

// ---------------- Kernel P: Wt = transpose(W) as bf16 hi/lo -----------------
// Wt layout: [branch][col 128][k 256] bf16. One block per (branch,col).
__global__ __launch_bounds__(256) void k_wprep(
    const float* __restrict__ Wx, const float* __restrict__ Wn,
    __bf16* __restrict__ WtH, __bf16* __restrict__ WtL)
{
    const int br  = blockIdx.x >> 7;
    const int col = blockIdx.x & 127;
    const int k   = threadIdx.x;
    const float v = (br ? Wn : Wx)[(size_t)k * HIDC + col];
    const __bf16 h = (__bf16)v;
    const __bf16 l = (__bf16)(v - (float)h);
    const size_t o = ((size_t)br * HIDC + col) * IN + k;
    WtH[o] = h;
    WtL[o] = l;
}

// ---------------- Kernel A: m2[r] = mean10(f2 rows) -------------------------
__global__ __launch_bounds__(512) void k_mean(
    const int* __restrict__ ids2, const float* __restrict__ feats,
    float* __restrict__ m2)
{
    const int wave = threadIdx.x >> 6;
    const int lane = threadIdx.x & 63;
    const int r    = blockIdx.x * 8 + wave;
    const int base = r * 10;
    float4 acc = make_float4(0.f, 0.f, 0.f, 0.f);
    #pragma unroll
    for (int kk = 0; kk < 10; ++kk) {
        const float4 v = ((const float4*)(feats + (size_t)ids2[base + kk] * IN))[lane];
        acc.x += v.x; acc.y += v.y; acc.z += v.z; acc.w += v.w;
    }
    acc.x *= 0.1f; acc.y *= 0.1f; acc.z *= 0.1f; acc.w *= 0.1f;
    ((float4*)(m2 + (size_t)r * IN))[lane] = acc;
}

// ---------------- Kernel B: h1 = relu([f1@Wx1+b, m2@Wn1+b]) via MFMA --------
// Block = 32 rows x one branch (NB = blockIdx.x & 1). 4 waves: wave (rh,ch)
// computes rows rh*16..+15, cols ch*64..+63 as 4 16x16 accum tiles.
// A staged in LDS as bf16 hi/lo, XOR-swizzled (elem ^= (row&7)<<3) to kill
// the 16-rows-same-column ds_read_b128 bank conflict (G4).
__global__ __launch_bounds__(256) void k_gemm(
    const int* __restrict__ ids1, const float* __restrict__ feats,
    const float* __restrict__ m2,
    const __bf16* __restrict__ WtH, const __bf16* __restrict__ WtL,
    const float* __restrict__ bx, const float* __restrict__ bn,
    float* __restrict__ h1)
{
    __shared__ __bf16 Ah[BRM * IN];
    __shared__ __bf16 Al[BRM * IN];
    const int tid = threadIdx.x;
    const int NB  = blockIdx.x & 1;
    const int r0  = (blockIdx.x >> 1) * BRM;

    // ---- stage 32 rows -> bf16 hi/lo in LDS (4 rows in parallel, float4)
    const int sub = tid & 63;
    const int rg  = tid >> 6;
    #pragma unroll
    for (int i = 0; i < BRM; i += 4) {
        const int rr = i + rg;
        const int r  = r0 + rr;
        const float4* src = NB ? (const float4*)(m2 + (size_t)r * IN)
                               : (const float4*)(feats + (size_t)ids1[r] * IN);
        const float4 v = src[sub];
        const __bf16 h0 = (__bf16)v.x, h1v = (__bf16)v.y,
                     h2 = (__bf16)v.z, h3 = (__bf16)v.w;
        bf16x4 hv = {h0, h1v, h2, h3};
        bf16x4 lv = {(__bf16)(v.x - (float)h0), (__bf16)(v.y - (float)h1v),
                     (__bf16)(v.z - (float)h2), (__bf16)(v.w - (float)h3)};
        const int e  = rr * IN + sub * 4;
        const int es = e ^ ((rr & 7) << 3);     // 16B-slot XOR swizzle
        *(bf16x4*)&Ah[es] = hv;
        *(bf16x4*)&Al[es] = lv;
    }
    __syncthreads();

    // ---- MFMA: wave (rh, ch); fragment layouts per cdna4 §3
    const int lane = tid & 63;
    const int wid  = tid >> 6;
    const int rh   = wid & 1;          // row half (16 rows)
    const int ch   = wid >> 1;         // col half (64 cols)
    const int l15  = lane & 15;
    const int lk   = lane >> 4;        // k sub-block / C row group
    const int arow = rh * 16 + l15;

    const __bf16* __restrict__ WH = WtH + (size_t)NB * HIDC * IN;
    const __bf16* __restrict__ WL = WtL + (size_t)NB * HIDC * IN;

    const f32x4 z = {0.f, 0.f, 0.f, 0.f};
    f32x4 acc[4] = {z, z, z, z};

    for (int k0 = 0; k0 < IN; k0 += 32) {
        int ea = arow * IN + k0 + lk * 8;
        ea ^= ((arow & 7) << 3);
        const bf16x8 aH = *(const bf16x8*)&Ah[ea];
        const bf16x8 aL = *(const bf16x8*)&Al[ea];
        #pragma unroll
        for (int ct = 0; ct < 4; ++ct) {
            const size_t eb = (size_t)(ch * 64 + ct * 16 + l15) * IN + k0 + lk * 8;
            const bf16x8 bH = *(const bf16x8*)&WH[eb];
            const bf16x8 bL = *(const bf16x8*)&WL[eb];
            acc[ct] = __builtin_amdgcn_mfma_f32_16x16x32_bf16(aH, bH, acc[ct], 0, 0, 0);
            acc[ct] = __builtin_amdgcn_mfma_f32_16x16x32_bf16(aH, bL, acc[ct], 0, 0, 0);
            acc[ct] = __builtin_amdgcn_mfma_f32_16x16x32_bf16(aL, bH, acc[ct], 0, 0, 0);
        }
    }

    // ---- epilogue: C/D col=lane&15, row=(lane>>4)*4+reg (m89-verified)
    const float* __restrict__ bias = NB ? bn : bx;
    #pragma unroll
    for (int ct = 0; ct < 4; ++ct) {
        const int colL = ch * 64 + ct * 16 + l15;   // 0..127 within branch
        const float bv = bias[colL];
        #pragma unroll
        for (int q = 0; q < 4; ++q) {
            const int rr = rh * 16 + lk * 4 + q;
            h1[(size_t)(r0 + rr) * IN + NB * HIDC + colL] =
                fmaxf(acc[ct][q] + bv, 0.f);
        }
    }
}

// ---------------- Kernel C: per output row, 512 threads ---------------------
__global__ __launch_bounds__(512) void k_out(
    const int* __restrict__ ids, const int* __restrict__ ids1,
    const float* __restrict__ feats, const float* __restrict__ h1,
    const float* __restrict__ Wx1, const float* __restrict__ bx1,
    const float* __restrict__ Wn1, const float* __restrict__ bn1,
    const float* __restrict__ Wx2, const float* __restrict__ bx2,
    const float* __restrict__ Wn2, const float* __restrict__ bn2,
    const float* __restrict__ Wfc, const float* __restrict__ bfc,
    float* __restrict__ out)
{
    __shared__ float x0[IN];
    __shared__ float m1[IN];
    __shared__ float mh[IN];
    __shared__ float h0[IN];
    __shared__ float g0[IN];
    __shared__ float partA[2][IN];
    __shared__ float partB[2][IN];
    __shared__ float red[8];
    __shared__ float fcred[7][4];
    const int i   = blockIdx.x;
    const int tid = threadIdx.x;
    const int c   = tid & 255;
    const int h   = tid >> 8;

    float s = 0.f, sh = 0.f;
    for (int kk = h; kk < 25; kk += 2) {
        const int r = i * 25 + kk;
        s  += feats[(size_t)ids1[r] * IN + c];
        sh += h1[(size_t)r * IN + c];
    }
    if (h == 0) x0[c] = feats[(size_t)ids[i] * IN + c];
    partA[h][c] = s;
    partB[h][c] = sh;
    __syncthreads();
    if (h == 0) m1[c] = (partA[0][c] + partA[1][c]) * 0.04f;
    else        mh[c] = (partB[0][c] + partB[1][c]) * 0.04f;
    __syncthreads();

    const int  jj = c & 127;
    const bool nb = (c >= 128);
    {
        const float* __restrict__ W = nb ? Wn1 : Wx1;
        const float* __restrict__ X = nb ? m1 : x0;
        float acc = 0.f;
        #pragma unroll 4
        for (int k = h * 128; k < h * 128 + 128; ++k)
            acc = fmaf(X[k], W[(size_t)k * HIDC + jj], acc);
        partA[h][c] = acc;
    }
    __syncthreads();
    if (h == 0)
        h0[c] = fmaxf(partA[0][c] + partA[1][c] + (nb ? bn1 : bx1)[jj], 0.f);
    __syncthreads();
    {
        const float* __restrict__ W = nb ? Wn2 : Wx2;
        const float* __restrict__ X = nb ? mh : h0;
        float acc = 0.f;
        #pragma unroll 4
        for (int k = h * 128; k < h * 128 + 128; ++k)
            acc = fmaf(X[k], W[(size_t)k * HIDC + jj], acc);
        partB[h][c] = acc;
    }
    __syncthreads();
    if (h == 0)
        g0[c] = partB[0][c] + partB[1][c] + (nb ? bn2 : bx2)[jj];
    __syncthreads();

    {
        const float gv = g0[c];
        float sq = gv * gv;
        #pragma unroll
        for (int off = 32; off > 0; off >>= 1) sq += __shfl_down(sq, off);
        if ((tid & 63) == 0) red[tid >> 6] = sq;
    }
    __syncthreads();
    const float total = (red[0] + red[1] + red[2] + red[3] +
                         red[4] + red[5] + red[6] + red[7]) * 0.5f;
    const float inv = 1.f / fmaxf(sqrtf(total), 1e-12f);
    const float p = g0[c] * inv;

    const int qbase = h * 4;
    const int qn    = h ? 3 : 4;
    for (int q = qbase; q < qbase + qn; ++q) {
        float t = p * Wfc[(size_t)c * 7 + q];
        #pragma unroll
        for (int off = 32; off > 0; off >>= 1) t += __shfl_down(t, off);
        if ((tid & 63) == 0) fcred[q][(tid >> 6) & 3] = t;
    }
    __syncthreads();
    if (tid < 7) {
        out[(size_t)i * 7 + tid] =
            fcred[tid][0] + fcred[tid][1] + fcred[tid][2] + fcred[tid][3] + bfc[tid];
    }
}

extern "C" void kernel_launch(void* const* d_in, const int* in_sizes, int n_in,
                              void* d_out, int out_size, void* d_ws, size_t ws_size,
                              hipStream_t stream) {
    const int*   ids   = (const int*)d_in[0];
    const int*   ids1  = (const int*)d_in[1];
    const int*   ids2  = (const int*)d_in[2];
    const float* feats = (const float*)d_in[3];
    const float* Wx1   = (const float*)d_in[4];
    const float* bx1   = (const float*)d_in[5];
    const float* Wn1   = (const float*)d_in[6];
    const float* bn1   = (const float*)d_in[7];
    const float* Wx2   = (const float*)d_in[8];
    const float* bx2   = (const float*)d_in[9];
    const float* Wn2   = (const float*)d_in[10];
    const float* bn2   = (const float*)d_in[11];
    const float* Wfc   = (const float*)d_in[12];
    const float* bfc   = (const float*)d_in[13];
    float* out = (float*)d_out;

    float*  m2  = (float*)d_ws;                         // [12800][256] f32
    float*  h1  = m2 + (size_t)ROWS1 * IN;              // [12800][256] f32
    __bf16* WtH = (__bf16*)(h1 + (size_t)ROWS1 * IN);   // [2][128][256] bf16
    __bf16* WtL = WtH + (size_t)2 * HIDC * IN;

    k_wprep<<<256, 256, 0, stream>>>(Wx1, Wn1, WtH, WtL);
    k_mean<<<ROWS1 / 8, 512, 0, stream>>>(ids2, feats, m2);
    k_gemm<<<(ROWS1 / BRM) * 2, 256, 0, stream>>>(ids1, feats, m2,
                                                  WtH, WtL, bx1, bn1, h1);
    k_out<<<512, 512, 0, stream>>>(ids, ids1, feats, h1,
                                   Wx1, bx1, Wn1, bn1,
                                   Wx2, bx2, Wn2, bn2,
                                   Wfc, bfc, out);
}

// Round 6
// 88.410 us; speedup vs baseline: 1.2486x; 1.0852x over previous
//
#include <hip/hip_runtime.h>
#include <hip/hip_bf16.h>

// GraphSAGE 2-layer forward.
// Layer-1 GEMM: A in bf16-hi, W in bf16 hi+lo, 2-pass MFMA (aH*wH + aH*wL).
// Error of dropped aL*w term ~1.8e-3 on h1, attenuated by mean25/normalize/FC
// to <2e-4 on out (threshold 3.2e-3).

typedef __bf16 bf16x8 __attribute__((ext_vector_type(8)));
typedef __bf16 bf16x4 __attribute__((ext_vector_type(4)));
typedef float  f32x4  __attribute__((ext_vector_type(4)));

constexpr int IN    = 256;
constexpr int HIDC  = 128;
constexpr int ROWS1 = 512 * 25;   // 12800

// ---------------- Kernel P: Wt = transpose(W) as bf16 hi/lo -----------------
// Wt layout: [branch][col 128][k 256] bf16.
__global__ __launch_bounds__(256) void k_wprep(
    const float* __restrict__ Wx, const float* __restrict__ Wn,
    __bf16* __restrict__ WtH, __bf16* __restrict__ WtL)
{
    const int br  = blockIdx.x >> 7;
    const int col = blockIdx.x & 127;
    const int k   = threadIdx.x;
    const float v = (br ? Wn : Wx)[(size_t)k * HIDC + col];
    const __bf16 h = (__bf16)v;
    const __bf16 l = (__bf16)(v - (float)h);
    const size_t o = ((size_t)br * HIDC + col) * IN + k;
    WtH[o] = h;
    WtL[o] = l;
}

// ---------------- Kernel A: gather f1 + mean10(f2) -> bf16-hi panels --------
// One wave per row r: 11 independent 1KB loads (max MLP, no LDS, max occupancy).
// A0[r] = bf16(f1 row), A1[r] = bf16(mean10 of f2 rows).
__global__ __launch_bounds__(512) void k_mean2(
    const int* __restrict__ ids1, const int* __restrict__ ids2,
    const float* __restrict__ feats,
    __bf16* __restrict__ A0, __bf16* __restrict__ A1)
{
    const int wave = threadIdx.x >> 6;
    const int lane = threadIdx.x & 63;
    const int r    = blockIdx.x * 8 + wave;
    const int base = r * 10;

    const float4 v1 = ((const float4*)(feats + (size_t)ids1[r] * IN))[lane];
    float4 acc = make_float4(0.f, 0.f, 0.f, 0.f);
    #pragma unroll
    for (int kk = 0; kk < 10; ++kk) {
        const float4 v = ((const float4*)(feats + (size_t)ids2[base + kk] * IN))[lane];
        acc.x += v.x; acc.y += v.y; acc.z += v.z; acc.w += v.w;
    }
    acc.x *= 0.1f; acc.y *= 0.1f; acc.z *= 0.1f; acc.w *= 0.1f;

    const bf16x4 a0 = {(__bf16)v1.x, (__bf16)v1.y, (__bf16)v1.z, (__bf16)v1.w};
    const bf16x4 a1 = {(__bf16)acc.x, (__bf16)acc.y, (__bf16)acc.z, (__bf16)acc.w};
    *(bf16x4*)&A0[(size_t)r * IN + lane * 4] = a0;
    *(bf16x4*)&A1[(size_t)r * IN + lane * 4] = a1;
}

// ---------------- Kernel B: h1 = relu([A0@Wx, A1@Wn] + b) via MFMA ----------
// Grid 1600: bid -> (row-tile rt of 16 rows, col-half cb). cb=0: self branch
// (A0, Wx cols 0..127); cb=1: neighbor (A1, Wn cols 128..255).
// 256 thr = 4 waves; wave w computes 16 rows x 32 cols (2 accum tiles).
// A tile staged in LDS (8 KB) with 16B-slot XOR swizzle -> conflict-free
// ds_read_b128 fragments.
__global__ __launch_bounds__(256) void k_gemm3(
    const __bf16* __restrict__ A0, const __bf16* __restrict__ A1,
    const __bf16* __restrict__ WtH, const __bf16* __restrict__ WtL,
    const float* __restrict__ bx, const float* __restrict__ bn,
    float* __restrict__ h1)
{
    __shared__ __bf16 As[16 * IN];
    const int tid = threadIdx.x;
    const int rt  = blockIdx.x >> 1;
    const int cb  = blockIdx.x & 1;
    const int r0  = rt * 16;
    const __bf16* __restrict__ Ap = cb ? A1 : A0;

    // stage 16 rows x 256 k (8 KB, contiguous in panel) with XOR swizzle
    #pragma unroll
    for (int i = 0; i < 2; ++i) {
        const int e = (tid + i * 256) * 8;             // elem idx, 8-aligned
        const bf16x8 v = *(const bf16x8*)&Ap[(size_t)r0 * IN + e];
        const int row = e >> 8;
        const int es  = e ^ ((row & 7) << 3);          // 16B-slot swizzle
        *(bf16x8*)&As[es] = v;
    }
    __syncthreads();

    const int lane = tid & 63;
    const int wid  = tid >> 6;          // 0..3 -> 32-col group
    const int l15  = lane & 15;
    const int lk   = lane >> 4;

    const __bf16* __restrict__ WH = WtH + (size_t)cb * HIDC * IN;
    const __bf16* __restrict__ WL = WtL + (size_t)cb * HIDC * IN;

    const f32x4 z = {0.f, 0.f, 0.f, 0.f};
    f32x4 acc[2] = {z, z};

    for (int k0 = 0; k0 < IN; k0 += 32) {
        int ea = (l15 << 8) + k0 + lk * 8;
        ea ^= (l15 & 7) << 3;
        const bf16x8 a = *(const bf16x8*)&As[ea];
        #pragma unroll
        for (int ct = 0; ct < 2; ++ct) {
            const size_t eb = (size_t)(wid * 32 + ct * 16 + l15) * IN + k0 + lk * 8;
            const bf16x8 bH = *(const bf16x8*)&WH[eb];
            const bf16x8 bL = *(const bf16x8*)&WL[eb];
            acc[ct] = __builtin_amdgcn_mfma_f32_16x16x32_bf16(a, bH, acc[ct], 0, 0, 0);
            acc[ct] = __builtin_amdgcn_mfma_f32_16x16x32_bf16(a, bL, acc[ct], 0, 0, 0);
        }
    }

    // epilogue: C/D col=lane&15, row=(lane>>4)*4+reg
    const float* __restrict__ bias = cb ? bn : bx;
    #pragma unroll
    for (int ct = 0; ct < 2; ++ct) {
        const int colL = wid * 32 + ct * 16 + l15;     // 0..127 within branch
        const float bv = bias[colL];
        #pragma unroll
        for (int q = 0; q < 4; ++q) {
            const int rr = lk * 4 + q;
            h1[(size_t)(r0 + rr) * IN + cb * HIDC + colL] =
                fmaxf(acc[ct][q] + bv, 0.f);
        }
    }
}

// ---------------- Kernel C: per output row, 512 threads ---------------------
// m1 now read from the contiguous A0 panel (bf16) instead of re-gathering f1.
__global__ __launch_bounds__(512) void k_out(
    const int* __restrict__ ids, const __bf16* __restrict__ A0,
    const float* __restrict__ feats, const float* __restrict__ h1,
    const float* __restrict__ Wx1, const float* __restrict__ bx1,
    const float* __restrict__ Wn1, const float* __restrict__ bn1,
    const float* __restrict__ Wx2, const float* __restrict__ bx2,
    const float* __restrict__ Wn2, const float* __restrict__ bn2,
    const float* __restrict__ Wfc, const float* __restrict__ bfc,
    float* __restrict__ out)
{
    __shared__ float x0[IN];
    __shared__ float m1[IN];
    __shared__ float mh[IN];
    __shared__ float h0[IN];
    __shared__ float g0[IN];
    __shared__ float partA[2][IN];
    __shared__ float partB[2][IN];
    __shared__ float red[8];
    __shared__ float fcred[7][4];
    const int i   = blockIdx.x;
    const int tid = threadIdx.x;
    const int c   = tid & 255;
    const int h   = tid >> 8;

    float s = 0.f, sh = 0.f;
    for (int kk = h; kk < 25; kk += 2) {
        const int r = i * 25 + kk;
        s  += (float)A0[(size_t)r * IN + c];
        sh += h1[(size_t)r * IN + c];
    }
    if (h == 0) x0[c] = feats[(size_t)ids[i] * IN + c];
    partA[h][c] = s;
    partB[h][c] = sh;
    __syncthreads();
    if (h == 0) m1[c] = (partA[0][c] + partA[1][c]) * 0.04f;
    else        mh[c] = (partB[0][c] + partB[1][c]) * 0.04f;
    __syncthreads();

    const int  jj = c & 127;
    const bool nb = (c >= 128);
    {
        const float* __restrict__ W = nb ? Wn1 : Wx1;
        const float* __restrict__ X = nb ? m1 : x0;
        float acc = 0.f;
        #pragma unroll 4
        for (int k = h * 128; k < h * 128 + 128; ++k)
            acc = fmaf(X[k], W[(size_t)k * HIDC + jj], acc);
        partA[h][c] = acc;
    }
    __syncthreads();
    if (h == 0)
        h0[c] = fmaxf(partA[0][c] + partA[1][c] + (nb ? bn1 : bx1)[jj], 0.f);
    __syncthreads();
    {
        const float* __restrict__ W = nb ? Wn2 : Wx2;
        const float* __restrict__ X = nb ? mh : h0;
        float acc = 0.f;
        #pragma unroll 4
        for (int k = h * 128; k < h * 128 + 128; ++k)
            acc = fmaf(X[k], W[(size_t)k * HIDC + jj], acc);
        partB[h][c] = acc;
    }
    __syncthreads();
    if (h == 0)
        g0[c] = partB[0][c] + partB[1][c] + (nb ? bn2 : bx2)[jj];
    __syncthreads();

    {
        const float gv = g0[c];
        float sq = gv * gv;
        #pragma unroll
        for (int off = 32; off > 0; off >>= 1) sq += __shfl_down(sq, off);
        if ((tid & 63) == 0) red[tid >> 6] = sq;
    }
    __syncthreads();
    const float total = (red[0] + red[1] + red[2] + red[3] +
                         red[4] + red[5] + red[6] + red[7]) * 0.5f;
    const float inv = 1.f / fmaxf(sqrtf(total), 1e-12f);
    const float p = g0[c] * inv;

    const int qbase = h * 4;
    const int qn    = h ? 3 : 4;
    for (int q = qbase; q < qbase + qn; ++q) {
        float t = p * Wfc[(size_t)c * 7 + q];
        #pragma unroll
        for (int off = 32; off > 0; off >>= 1) t += __shfl_down(t, off);
        if ((tid & 63) == 0) fcred[q][(tid >> 6) & 3] = t;
    }
    __syncthreads();
    if (tid < 7) {
        out[(size_t)i * 7 + tid] =
            fcred[tid][0] + fcred[tid][1] + fcred[tid][2] + fcred[tid][3] + bfc[tid];
    }
}

extern "C" void kernel_launch(void* const* d_in, const int* in_sizes, int n_in,
                              void* d_out, int out_size, void* d_ws, size_t ws_size,
                              hipStream_t stream) {
    const int*   ids   = (const int*)d_in[0];
    const int*   ids1  = (const int*)d_in[1];
    const int*   ids2  = (const int*)d_in[2];
    const float* feats = (const float*)d_in[3];
    const float* Wx1   = (const float*)d_in[4];
    const float* bx1   = (const float*)d_in[5];
    const float* Wn1   = (const float*)d_in[6];
    const float* bn1   = (const float*)d_in[7];
    const float* Wx2   = (const float*)d_in[8];
    const float* bx2   = (const float*)d_in[9];
    const float* Wn2   = (const float*)d_in[10];
    const float* bn2   = (const float*)d_in[11];
    const float* Wfc   = (const float*)d_in[12];
    const float* bfc   = (const float*)d_in[13];
    float* out = (float*)d_out;

    __bf16* A0  = (__bf16*)d_ws;                      // [12800][256] bf16
    __bf16* A1  = A0 + (size_t)ROWS1 * IN;            // [12800][256] bf16
    float*  h1  = (float*)(A1 + (size_t)ROWS1 * IN);  // [12800][256] f32
    __bf16* WtH = (__bf16*)(h1 + (size_t)ROWS1 * IN); // [2][128][256] bf16
    __bf16* WtL = WtH + (size_t)2 * HIDC * IN;

    k_wprep<<<256, 256, 0, stream>>>(Wx1, Wn1, WtH, WtL);
    k_mean2<<<ROWS1 / 8, 512, 0, stream>>>(ids1, ids2, feats, A0, A1);
    k_gemm3<<<(ROWS1 / 16) * 2, 256, 0, stream>>>(A0, A1, WtH, WtL, bx1, bn1, h1);
    k_out<<<512, 512, 0, stream>>>(ids, A0, feats, h1,
                                   Wx1, bx1, Wn1, bn1,
                                   Wx2, bx2, Wn2, bn2,
                                   Wfc, bfc, out);
}